// Round 6
// baseline (17122.604 us; speedup 1.0000x reference)
//
#include <hip/hip_runtime.h>
#include <hip/hip_cooperative_groups.h>
#include <math.h>

namespace cg = cooperative_groups;

#define NN 4096
#define TT 64
#define HH 128
#define NNP 4160            // hinT row stride (shorts): 8320B kills 8KB L2 set-aliasing
#define SPLITS 16
#define KPB (NN / SPLITS)   // 256 keys per phase-A block
#define KT 32
#define NTILES (KPB / KT)   // 8
#define SCALE 0.08838834764831845f   // 1/sqrt(128)
#define CSHIFT 16.0f

typedef __attribute__((ext_vector_type(8))) short short8;
typedef __attribute__((ext_vector_type(4))) float f32x4;
typedef unsigned long long u64;
#define MFMA(a, b, c)   __builtin_amdgcn_mfma_f32_16x16x32_bf16((a), (b), (c), 0, 0, 0)

// ---- bf16 helpers (RNE) ----
__device__ __forceinline__ short f2b(float f) {
    union { float f; unsigned u; } v; v.f = f;
    unsigned r = v.u + 0x7fffu + ((v.u >> 16) & 1u);
    return (short)(r >> 16);
}
__device__ __forceinline__ float b2f(short s) {
    union { unsigned u; float f; } v; v.u = ((unsigned)(unsigned short)s) << 16;
    return v.f;
}
// Wave-local LDS fence: completes ds ops + blocks compiler reordering of
// cross-lane LDS accesses without a block barrier.
__device__ __forceinline__ void lds_fence() {
    __asm__ __volatile__("s_waitcnt lgkmcnt(0)" ::: "memory");
}

// ===========================================================================
// hinT column permutation sigma (within each 32-column group):
//   column c holds node  sigma(c) = (c&4) ? 16 + 4*(c>>3) + (c&3)
//                                         :      4*(c>>3) + (c&3)
// Writers place node kk at column inv_sigma(kk) = ((kk>>2)&3)*8 +
// ((kk>>4)&1)*4 + (kk&3).  After swapped QK^T (st = MFMA(K,Q) -> D[key][q]),
// lane (ln,g) holds the 8 P-values of query qt*16+ln for keys
// {4g..4g+3, 16+4g..16+4g+3} — exactly a 16x16x32 PV A-fragment under sigma
// on the key axis.  PV's key axis is a dot product, so permuting BOTH
// P-slots and V-slots by sigma is free.  (R3-proven end to end.)
// l accumulates on the matrix pipe via a B=ones MFMA (R5-proven,
// layout-independent).  cvt_pk inline asm is BANNED (NaN in R1/R2/R4).
// ===========================================================================

// ===========================================================================
// prep: once per launch. bf16 weight transposes; hp = b_proj (h0=0);
// hinT (padded stride NNP, sigma-permuted columns) from x[:,0], m[:,0].
// ===========================================================================
__global__ __launch_bounds__(256) void prep_kernel(
    const float* __restrict__ x_seq, const float* __restrict__ m_seq,
    const float* __restrict__ W_in,  const float* __restrict__ b_in,
    const float* __restrict__ W_proj,const float* __restrict__ b_proj,
    const float* __restrict__ W_gcn,
    short* __restrict__ hp, short* __restrict__ hinT,
    short* __restrict__ WgT, short* __restrict__ WpT)
{
    const int b = blockIdx.x, tid = threadIdx.x;
    if (b < 256) {
        const int n0 = b * 16;
        for (int i = tid; i < 16 * HH; i += 256) {
            const int q = i >> 7, j = i & 127, n = n0 + q;
            hp[n * HH + j] = f2b(b_proj[j]);
            float hv = x_seq[n * TT] * W_in[j] + m_seq[n * TT] * W_in[HH + j] + b_in[j];
            hv = hv > 0.f ? hv : 0.f;
            // col = (n & ~31) | inv_sigma(n & 31)
            const int col = (n & ~31) | (((n >> 2) & 3) << 3) | (((n >> 4) & 1) << 2) | (n & 3);
            hinT[(size_t)j * NNP + col] = f2b(hv);
        }
    } else {
        const int wb = b - 256;
        #pragma unroll
        for (int k = 0; k < 4; ++k) {
            const int idx = wb * 1024 + k * 256 + tid;   // = n*128 + kk
            const int n = idx >> 7, kk = idx & 127;
            WgT[idx] = f2b(W_gcn[kk * HH + n]);
            WpT[idx] = f2b(W_proj[kk * HH + n]);
        }
    }
}

// ===========================================================================
// Persistent cooperative kernel: ONE launch, 256 blocks x 512 thr (1 blk/CU),
// loops t = 0..63 with grid.sync() + __threadfence() replacing the 128 kernel
// boundaries (fences provide release/writeback + acquire/invalidate across
// the non-coherent per-XCD L2s, which kernel boundaries used to provide).
//
// ATTN phase (R3-proven body): 8 waves, wave owns 32 q rows (2 q-tiles); all
// waves share the block's 256-key slice via LDS-staged double-buffered K/V
// tiles, ONE barrier/tile.  Swapped QK^T -> in-register f2b softmax -> PV via
// sigma.  l on the matrix pipe (ones column).  O partials out bf16 via the
// per-wave LDS bounce.
//
// FUSE phase: barriers hoisted to all 512 threads; merge at 256 thr (proven
// pattern); GEMM1/GEMM2 widened to 8 waves (nt = wave); pred partials 8x16.
// ===========================================================================
__global__ __launch_bounds__(512, 2) void step_kernel(
    short* __restrict__ hp, short* __restrict__ hinT,
    const short* __restrict__ WgT, const short* __restrict__ WpT,
    short* __restrict__ OpartB, float* __restrict__ lpart,
    const float* __restrict__ b_gcn, const float* __restrict__ b_proj,
    const float* __restrict__ W_out, const float* __restrict__ b_out,
    const float* __restrict__ x_seq, const float* __restrict__ m_seq,
    const float* __restrict__ W_in,  const float* __restrict__ b_in,
    float* __restrict__ out)
{
    cg::grid_group grid = cg::this_grid();

    __shared__ __align__(16) char pool[37888];
    short* KtS = (short*)pool;                  // [2][32*136]  17408 B
    short* VtS = (short*)(pool + 17408);        // [2][128*40]  20480 B
    __shared__ __align__(16) short msgb[16 * 136];
    __shared__ __align__(16) short hnb[16 * 136];
    __shared__ __align__(16) short hintb[128 * 16];
    __shared__ float larr[16];
    __shared__ float ppd[8 * 16];

    const int tid  = threadIdx.x;
    const int wave = tid >> 6, lane = tid & 63;
    const int ln = lane & 15, g = lane >> 4;
    const int blk = blockIdx.x;
    const int qg = blk >> 4, split = blk & 15;   // attn role
    const int q0 = qg * 256 + wave * 32;
    const int kbase = split * KPB;
    const int qb = blk * 16;                     // fuse role

    // staging thread maps (512 threads, 16B/lane coalesced)
    const int krow = tid >> 4, kcol = (tid & 15) * 8;   // 32 rows x 128 shorts
    const int vrow = tid >> 2, vcol = (tid & 3) * 8;    // 128 rows x 32 shorts

    short8 vone;
    #pragma unroll
    for (int e = 0; e < 8; ++e) vone[e] = (short)0x3F80;   // bf16 1.0

    for (int t = 0; t < TT; ++t) {
        // ============================ ATTN ============================
        // Q fragments (B-operand in swapped QK^T): 2 q-tiles, proven layout
        short8 qf[2][4];
        #pragma unroll
        for (int qt = 0; qt < 2; ++qt)
            #pragma unroll
            for (int kc = 0; kc < 4; ++kc)
                qf[qt][kc] = *(const short8*)&hp[(q0 + qt * 16 + ln) * HH + kc * 32 + g * 8];

        f32x4 oacc[2][8] = {};   // O[q = qt*16 + g*4 + r][d = dt*16 + ln]
        f32x4 lacc[2] = {};      // l (ones-column accumulator)

        short8 ksA, vsA;
        auto load_tile = [&](int kt_) {
            const int kb = kbase + kt_ * KT;
            ksA = *(const short8*)&hp  [(kb + krow) * HH + kcol];
            vsA = *(const short8*)&hinT[(size_t)vrow * NNP + kb + vcol];
        };
        auto store_tile = [&](int b) {
            *(short8*)&KtS[b * 4352 + krow * 136 + kcol] = ksA;
            *(short8*)&VtS[b * 5120 + vrow * 40 + vcol]  = vsA;
        };

        load_tile(0);
        store_tile(0);

        for (int kt = 0; kt < NTILES; ++kt) {
            const int b = kt & 1;
            __syncthreads();   // buf b staged; prev iter's frag reads drained (WAR)

            short8 kf[2][4], vf[8];
            #pragma unroll
            for (int kt2 = 0; kt2 < 2; ++kt2)
                #pragma unroll
                for (int kc = 0; kc < 4; ++kc)
                    kf[kt2][kc] = *(const short8*)&KtS[b * 4352 + (kt2 * 16 + ln) * 136 + kc * 32 + g * 8];
            #pragma unroll
            for (int dt = 0; dt < 8; ++dt)
                vf[dt] = *(const short8*)&VtS[b * 5120 + (dt * 16 + ln) * 40 + g * 8];

            if (kt + 1 < NTILES) load_tile(kt + 1);   // global -> regs, overlaps compute

            // swapped scores: st[kt2][qt][r] = S[key = kt2*16+g*4+r][q = qt*16+ln]
            f32x4 st[2][2] = {};
            __builtin_amdgcn_s_setprio(1);
            #pragma unroll
            for (int kt2 = 0; kt2 < 2; ++kt2)
                #pragma unroll
                for (int qt = 0; qt < 2; ++qt)
                    #pragma unroll
                    for (int kc = 0; kc < 4; ++kc)
                        st[kt2][qt] = MFMA(kf[kt2][kc], qf[qt][kc], st[kt2][qt]);
            __builtin_amdgcn_s_setprio(0);

            // fixed-shift softmax numerators -> bf16 A-fragments (proven order)
            short8 pa[2];
            #pragma unroll
            for (int qt = 0; qt < 2; ++qt) {
                short8 paq;
                #pragma unroll
                for (int e = 0; e < 8; ++e) {
                    const float s = (e < 4) ? st[0][qt][e] : st[1][qt][e - 4];
                    paq[e] = f2b(__expf(s * SCALE - CSHIFT));
                }
                pa[qt] = paq;
            }

            if (kt + 1 < NTILES) store_tile(b ^ 1);

            // PV (+ l via ones column): pa[qt] is the A-fragment in slot space
            __builtin_amdgcn_s_setprio(1);
            #pragma unroll
            for (int qt = 0; qt < 2; ++qt) {
                #pragma unroll
                for (int dt = 0; dt < 8; ++dt)
                    oacc[qt][dt] = MFMA(pa[qt], vf[dt], oacc[qt][dt]);
                lacc[qt] = MFMA(pa[qt], vone, lacc[qt]);
            }
            __builtin_amdgcn_s_setprio(0);
        }

        __syncthreads();   // all waves' LDS frag reads done -> pool reusable as bounce

        // l: ones-column output is col-replicated; row q = g*4 + r
        #pragma unroll
        for (int qt = 0; qt < 2; ++qt)
            if (ln == 0) {
                #pragma unroll
                for (int r = 0; r < 4; ++r)
                    lpart[split * NN + q0 + qt * 16 + g * 4 + r] = lacc[qt][r];
            }

        // O partials -> bf16 via per-wave LDS bounce (coalesced 16B/lane stores)
        short* bounce = (short*)pool + wave * 2048;   // 4KB/wave in dead Kt/Vt
        #pragma unroll
        for (int qt = 0; qt < 2; ++qt) {
            #pragma unroll
            for (int dt = 0; dt < 8; ++dt)
                #pragma unroll
                for (int r = 0; r < 4; ++r)
                    bounce[(g * 4 + r) * 128 + dt * 16 + ln] = f2b(oacc[qt][dt][r]);
            lds_fence();   // RAW: cross-lane bounce writes before row reads
            #pragma unroll
            for (int sub = 0; sub < 4; ++sub) {
                const int qrow = sub * 4 + (lane >> 4), chunk = lane & 15;
                const short8 rd = *(const short8*)&bounce[qrow * 128 + chunk * 8];
                *(short8*)&OpartB[((size_t)split * NN + q0 + qt * 16 + qrow) * HH + chunk * 8] = rd;
            }
            lds_fence();   // WAR before next qt overwrites the bounce
        }

        __threadfence();   // release: OpartB/lpart visible device-wide
        grid.sync();
        __threadfence();   // acquire: invalidate stale partials in this XCD's caches

        // ============================ FUSE ============================
        if (tid < 16) {
            float l = 0.f;
            #pragma unroll
            for (int sp = 0; sp < SPLITS; ++sp) l += lpart[sp * NN + qb + tid];
            larr[tid] = 1.0f / l;
        }
        __syncthreads();

        // merge 16 bf16 partials -> msg (256 thr, short8 coalesced, fp32 acc)
        if (tid < 256) {
            const int q = tid >> 4, c8 = (tid & 15) * 8;
            float s[8] = {0.f, 0.f, 0.f, 0.f, 0.f, 0.f, 0.f, 0.f};
            #pragma unroll
            for (int sp = 0; sp < SPLITS; ++sp) {
                const short8 v = *(const short8*)&OpartB[((size_t)sp * NN + qb + q) * HH + c8];
                #pragma unroll
                for (int k = 0; k < 8; ++k) s[k] += b2f(v[k]);
            }
            const float inv = larr[q];
            short* mp = &msgb[q * 136 + c8];
            #pragma unroll
            for (int k = 0; k < 8; ++k) mp[k] = f2b(s[k] * inv);
        }
        __syncthreads();

        // GEMM1 (8 waves, nt = wave): h_new = relu(msg@Wg + b_gcn + h_in(t))
        {
            short8 af[4];
            #pragma unroll
            for (int kc = 0; kc < 4; ++kc)
                af[kc] = *(const short8*)&msgb[ln * 136 + kc * 32 + g * 8];
            f32x4 c = {};
            #pragma unroll
            for (int kc = 0; kc < 4; ++kc)
                c = MFMA(af[kc], *(const short8*)&WgT[(wave * 16 + ln) * HH + kc * 32 + g * 8], c);
            const int j = wave * 16 + ln;
            const float bg = b_gcn[j], wo = W_out[j];
            const float wj0 = W_in[j], wj1 = W_in[HH + j], bj = b_in[j];
            float pr[4];
            #pragma unroll
            for (int r = 0; r < 4; ++r) {
                const int q = g * 4 + r;
                float hv = x_seq[(qb + q) * TT + t] * wj0 + m_seq[(qb + q) * TT + t] * wj1 + bj;
                hv = hv > 0.f ? hv : 0.f;
                float v = c[r] + bg + b2f(f2b(hv));
                v = v > 0.f ? v : 0.f;
                hnb[q * 136 + j] = f2b(v);
                pr[r] = v * wo;
            }
            #pragma unroll
            for (int r = 0; r < 4; ++r) {
                float p = pr[r];
                p += __shfl_xor(p, 1); p += __shfl_xor(p, 2);
                p += __shfl_xor(p, 4); p += __shfl_xor(p, 8);
                if (ln == 0) ppd[wave * 16 + g * 4 + r] = p;
            }
        }
        __syncthreads();   // hnb + ppd complete

        if (tid < 16) {
            float s = b_out[0];
            #pragma unroll
            for (int w = 0; w < 8; ++w) s += ppd[w * 16 + tid];
            out[(qb + tid) * TT + t] = s;
        }

        if (t < TT - 1) {
            // GEMM2 (8 waves, nt = wave): h_proj(t+1) = h_new @ W_proj + b_proj
            {
                short8 hf[4];
                #pragma unroll
                for (int kc = 0; kc < 4; ++kc)
                    hf[kc] = *(const short8*)&hnb[ln * 136 + kc * 32 + g * 8];
                f32x4 c = {};
                #pragma unroll
                for (int kc = 0; kc < 4; ++kc)
                    c = MFMA(hf[kc], *(const short8*)&WpT[(wave * 16 + ln) * HH + kc * 32 + g * 8], c);
                const float bp = b_proj[wave * 16 + ln];
                #pragma unroll
                for (int r = 0; r < 4; ++r)
                    hp[(qb + g * 4 + r) * HH + wave * 16 + ln] = f2b(c[r] + bp);
            }

            // h_in(t+1): LDS transpose (256 thr, proven) then sigma-permuted stores
            if (tid < 256) {
                for (int i = tid; i < 16 * HH; i += 256) {
                    const int q = i >> 7, j = i & 127;
                    float hv = x_seq[(qb + q) * TT + t + 1] * W_in[j]
                             + m_seq[(qb + q) * TT + t + 1] * W_in[HH + j] + b_in[j];
                    hv = hv > 0.f ? hv : 0.f;
                    hintb[j * 16 + q] = f2b(hv);
                }
            }
            __syncthreads();
            if (tid < 256) {
                for (int c = tid; c < 512; c += 256) {
                    const int j = c >> 2, off = (c & 3) * 4;
                    const int nb = qb + off;
                    const int tcol = (nb & ~31) | (((nb >> 2) & 3) << 3) | (((nb >> 4) & 1) << 2);
                    *(u64*)&hinT[(size_t)j * NNP + tcol] = *(const u64*)&hintb[j * 16 + off];
                }
            }
        }

        __threadfence();   // release: hp/hinT visible device-wide
        grid.sync();
        __threadfence();   // acquire: invalidate stale state before next attn
    }
}

// ===========================================================================
extern "C" void kernel_launch(void* const* d_in, const int* in_sizes, int n_in,
                              void* d_out, int out_size, void* d_ws, size_t ws_size,
                              hipStream_t stream) {
    const float* x_seq  = (const float*)d_in[0];
    const float* m_seq  = (const float*)d_in[1];
    const float* W_in   = (const float*)d_in[2];
    const float* b_in   = (const float*)d_in[3];
    const float* W_proj = (const float*)d_in[4];
    const float* b_proj = (const float*)d_in[5];
    const float* W_gcn  = (const float*)d_in[6];
    const float* b_gcn  = (const float*)d_in[7];
    const float* W_out  = (const float*)d_in[8];
    const float* b_out  = (const float*)d_in[9];
    float* out = (float*)d_out;

    // ws carve (~20 MB): hp | hinT(padded) | WgT | WpT | lpart | OpartB
    char* base = (char*)d_ws;
    const size_t MB = 1 << 20;
    short* hp     = (short*)(base + 0 * MB);
    short* hinT   = (short*)(base + 1 * MB);           // 128*4160*2 B
    short* WgT    = (short*)(base + 3 * MB);
    short* WpT    = (short*)(base + 3 * MB + 32768);
    float* lpart  = (float*)(base + 3 * MB + 65536);   // 16*4096*4 = 256 KB
    short* OpartB = (short*)(base + 4 * MB);           // 16*4096*128*2 = 16 MB

    prep_kernel<<<272, 256, 0, stream>>>(x_seq, m_seq, W_in, b_in, W_proj, b_proj,
                                         W_gcn, hp, hinT, WgT, WpT);

    void* kargs[] = {
        (void*)&hp, (void*)&hinT, (void*)&WgT, (void*)&WpT,
        (void*)&OpartB, (void*)&lpart,
        (void*)&b_gcn, (void*)&b_proj, (void*)&W_out, (void*)&b_out,
        (void*)&x_seq, (void*)&m_seq, (void*)&W_in, (void*)&b_in,
        (void*)&out
    };
    hipLaunchCooperativeKernel((const void*)step_kernel, dim3(256), dim3(512),
                               kargs, 0, stream);
}

// Round 7
// 2021.946 us; speedup vs baseline: 8.4684x; 8.4684x over previous
//
#include <hip/hip_runtime.h>
#include <math.h>

#define NN 4096
#define TT 64
#define HH 128
#define NNP 4160            // hinT row stride (shorts): 8320B kills 8KB L2 set-aliasing
#define SPLITS 16
#define KPB (NN / SPLITS)   // 256 keys per phase-A block
#define KT 32
#define NTILES (KPB / KT)   // 8
#define QB 128              // q rows per attn block (4 waves x 32)
#define SCALE 0.08838834764831845f   // 1/sqrt(128)
#define CSHIFT 16.0f

typedef __attribute__((ext_vector_type(8))) short short8;
typedef __attribute__((ext_vector_type(4))) float f32x4;
typedef unsigned long long u64;
#define MFMA(a, b, c)   __builtin_amdgcn_mfma_f32_16x16x32_bf16((a), (b), (c), 0, 0, 0)

// ---- bf16 helpers (RNE) ----
__device__ __forceinline__ short f2b(float f) {
    union { float f; unsigned u; } v; v.f = f;
    unsigned r = v.u + 0x7fffu + ((v.u >> 16) & 1u);
    return (short)(r >> 16);
}
__device__ __forceinline__ float b2f(short s) {
    union { unsigned u; float f; } v; v.u = ((unsigned)(unsigned short)s) << 16;
    return v.f;
}
// Wave-local LDS fence: completes ds ops + blocks compiler reordering of
// cross-lane LDS accesses without a block barrier.
__device__ __forceinline__ void lds_fence() {
    __asm__ __volatile__("s_waitcnt lgkmcnt(0)" ::: "memory");
}

// ===========================================================================
// hinT column permutation sigma (within each 32-column group):
//   column c holds node  sigma(c) = (c&4) ? 16 + 4*(c>>3) + (c&3)
//                                         :      4*(c>>3) + (c&3)
// Writers place node kk at column inv_sigma(kk) = ((kk>>2)&3)*8 +
// ((kk>>4)&1)*4 + (kk&3).  After swapped QK^T (st = MFMA(K,Q) -> D[key][q]),
// lane (ln,g) holds the 8 P-values of query qt*16+ln for keys
// {4g..4g+3, 16+4g..16+4g+3} — exactly a 16x16x32 PV A-fragment under sigma
// on the key axis (dot-product axis: permuting BOTH operands is free).
// R3-proven end to end.  l accumulates on the matrix pipe via a B=ones MFMA
// (R5/R6-proven, layout-independent).  cvt_pk inline asm BANNED (NaN R1/2/4).
// R6 lesson: device-scope fences (coop grid.sync) force L2 invalidation ->
// 23 MB/step HBM re-fetch; kernel boundaries are CHEAPER.  Stay multi-launch.
// ===========================================================================

// ===========================================================================
// prep: once per launch. bf16 weight transposes; hp = b_proj (h0=0);
// hinT (padded stride NNP, sigma-permuted columns) from x[:,0], m[:,0].
// ===========================================================================
__global__ __launch_bounds__(256) void prep_kernel(
    const float* __restrict__ x_seq, const float* __restrict__ m_seq,
    const float* __restrict__ W_in,  const float* __restrict__ b_in,
    const float* __restrict__ W_proj,const float* __restrict__ b_proj,
    const float* __restrict__ W_gcn,
    short* __restrict__ hp, short* __restrict__ hinT,
    short* __restrict__ WgT, short* __restrict__ WpT)
{
    const int b = blockIdx.x, tid = threadIdx.x;
    if (b < 256) {
        const int n0 = b * 16;
        for (int i = tid; i < 16 * HH; i += 256) {
            const int q = i >> 7, j = i & 127, n = n0 + q;
            hp[n * HH + j] = f2b(b_proj[j]);
            float hv = x_seq[n * TT] * W_in[j] + m_seq[n * TT] * W_in[HH + j] + b_in[j];
            hv = hv > 0.f ? hv : 0.f;
            // col = (n & ~31) | inv_sigma(n & 31)
            const int col = (n & ~31) | (((n >> 2) & 3) << 3) | (((n >> 4) & 1) << 2) | (n & 3);
            hinT[(size_t)j * NNP + col] = f2b(hv);
        }
    } else {
        const int wb = b - 256;
        #pragma unroll
        for (int k = 0; k < 4; ++k) {
            const int idx = wb * 1024 + k * 256 + tid;   // = n*128 + kk
            const int n = idx >> 7, kk = idx & 127;
            WgT[idx] = f2b(W_gcn[kk * HH + n]);
            WpT[idx] = f2b(W_proj[kk * HH + n]);
        }
    }
}

// ===========================================================================
// Phase A: attention partials. 512 blocks (32 qg x 16 splits) x 256 thr
// (4 waves) -> TWO co-resident blocks per CU (LDS 2x37KB), giving two
// INDEPENDENT barrier domains: when one block drains at its tile barrier,
// the other block's waves keep the MFMA/VALU/mem pipes busy (m114 overlap —
// unavailable in the old 1-block/CU layout).  Per-wave code is identical to
// the R3-proven body: wave owns 32 q rows (2 q-tiles), block stages its
// 256-key slice via LDS double-buffered K/V tiles, ONE barrier/tile.
// Swapped QK^T -> in-register f2b softmax -> PV via sigma; l on the matrix
// pipe (ones column, R6-proven).  O partials out bf16 via per-wave bounce.
// ===========================================================================
__global__ __launch_bounds__(256, 2) void attn_kernel(
    const short* __restrict__ hp, const short* __restrict__ hinT,
    short* __restrict__ OpartB, float* __restrict__ lpart)
{
    __shared__ __align__(16) char pool[37888];
    short* KtS = (short*)pool;                  // [2][32*136]  17408 B
    short* VtS = (short*)(pool + 17408);        // [2][128*40]  20480 B

    const int tid  = threadIdx.x;
    const int wave = tid >> 6, lane = tid & 63;
    const int ln = lane & 15, g = lane >> 4;
    const int qg = blockIdx.x >> 4, split = blockIdx.x & 15;
    const int q0 = qg * QB + wave * 32;
    const int kbase = split * KPB;

    // staging thread maps (256 threads, 16B/lane coalesced, 2 passes each)
    const int krow = tid >> 4, kcol = (tid & 15) * 8;   // rows 0..15 (+16)
    const int vrow = tid >> 2, vcol = (tid & 3) * 8;    // rows 0..63 (+64)

    // Q fragments (B-operand in swapped QK^T): 2 q-tiles, proven layout
    short8 qf[2][4];
    #pragma unroll
    for (int qt = 0; qt < 2; ++qt)
        #pragma unroll
        for (int kc = 0; kc < 4; ++kc)
            qf[qt][kc] = *(const short8*)&hp[(q0 + qt * 16 + ln) * HH + kc * 32 + g * 8];

    f32x4 oacc[2][8] = {};   // O[q = qt*16 + g*4 + r][d = dt*16 + ln]
    f32x4 lacc[2] = {};      // l (ones-column accumulator, matrix pipe)
    short8 vone;
    #pragma unroll
    for (int e = 0; e < 8; ++e) vone[e] = (short)0x3F80;   // bf16 1.0

    short8 ksA0, ksA1, vsA0, vsA1;
    auto load_tile = [&](int kt_) {
        const int kb = kbase + kt_ * KT;
        ksA0 = *(const short8*)&hp  [(kb + krow) * HH + kcol];
        ksA1 = *(const short8*)&hp  [(kb + krow + 16) * HH + kcol];
        vsA0 = *(const short8*)&hinT[(size_t)vrow * NNP + kb + vcol];
        vsA1 = *(const short8*)&hinT[(size_t)(vrow + 64) * NNP + kb + vcol];
    };
    auto store_tile = [&](int b) {
        *(short8*)&KtS[b * 4352 + krow * 136 + kcol]        = ksA0;
        *(short8*)&KtS[b * 4352 + (krow + 16) * 136 + kcol] = ksA1;
        *(short8*)&VtS[b * 5120 + vrow * 40 + vcol]         = vsA0;
        *(short8*)&VtS[b * 5120 + (vrow + 64) * 40 + vcol]  = vsA1;
    };

    load_tile(0);
    store_tile(0);

    for (int kt = 0; kt < NTILES; ++kt) {
        const int b = kt & 1;
        __syncthreads();   // buf b staged; prev iter's frag reads drained (WAR)

        short8 kf[2][4], vf[8];
        #pragma unroll
        for (int kt2 = 0; kt2 < 2; ++kt2)
            #pragma unroll
            for (int kc = 0; kc < 4; ++kc)
                kf[kt2][kc] = *(const short8*)&KtS[b * 4352 + (kt2 * 16 + ln) * 136 + kc * 32 + g * 8];
        #pragma unroll
        for (int dt = 0; dt < 8; ++dt)
            vf[dt] = *(const short8*)&VtS[b * 5120 + (dt * 16 + ln) * 40 + g * 8];

        if (kt + 1 < NTILES) load_tile(kt + 1);   // global -> regs, overlaps compute

        // swapped scores: st[kt2][qt][r] = S[key = kt2*16+g*4+r][q = qt*16+ln]
        f32x4 st[2][2] = {};
        __builtin_amdgcn_s_setprio(1);
        #pragma unroll
        for (int kt2 = 0; kt2 < 2; ++kt2)
            #pragma unroll
            for (int qt = 0; qt < 2; ++qt)
                #pragma unroll
                for (int kc = 0; kc < 4; ++kc)
                    st[kt2][qt] = MFMA(kf[kt2][kc], qf[qt][kc], st[kt2][qt]);
        __builtin_amdgcn_s_setprio(0);

        // fixed-shift softmax numerators -> bf16 A-fragments (proven order)
        short8 pa[2];
        #pragma unroll
        for (int qt = 0; qt < 2; ++qt) {
            short8 paq;
            #pragma unroll
            for (int e = 0; e < 8; ++e) {
                const float s = (e < 4) ? st[0][qt][e] : st[1][qt][e - 4];
                paq[e] = f2b(__expf(s * SCALE - CSHIFT));
            }
            pa[qt] = paq;
        }

        if (kt + 1 < NTILES) store_tile(b ^ 1);

        // PV (+ l via ones column): pa[qt] is the A-fragment in slot space
        __builtin_amdgcn_s_setprio(1);
        #pragma unroll
        for (int qt = 0; qt < 2; ++qt) {
            #pragma unroll
            for (int dt = 0; dt < 8; ++dt)
                oacc[qt][dt] = MFMA(pa[qt], vf[dt], oacc[qt][dt]);
            lacc[qt] = MFMA(pa[qt], vone, lacc[qt]);
        }
        __builtin_amdgcn_s_setprio(0);
    }

    __syncthreads();   // all waves' LDS frag reads done -> pool reusable as bounce

    // l: ones-column output is col-replicated; row q = g*4 + r (proven D map)
    #pragma unroll
    for (int qt = 0; qt < 2; ++qt)
        if (ln == 0) {
            #pragma unroll
            for (int r = 0; r < 4; ++r)
                lpart[split * NN + q0 + qt * 16 + g * 4 + r] = lacc[qt][r];
        }

    // O partials -> bf16 via per-wave LDS bounce (coalesced 16B/lane stores)
    short* bounce = (short*)pool + wave * 2048;   // 4KB/wave in dead Kt/Vt
    #pragma unroll
    for (int qt = 0; qt < 2; ++qt) {
        #pragma unroll
        for (int dt = 0; dt < 8; ++dt)
            #pragma unroll
            for (int r = 0; r < 4; ++r)
                bounce[(g * 4 + r) * 128 + dt * 16 + ln] = f2b(oacc[qt][dt][r]);
        lds_fence();   // RAW: cross-lane bounce writes before row reads
        #pragma unroll
        for (int sub = 0; sub < 4; ++sub) {
            const int qrow = sub * 4 + (lane >> 4), chunk = lane & 15;
            const short8 rd = *(const short8*)&bounce[qrow * 128 + chunk * 8];
            *(short8*)&OpartB[((size_t)split * NN + q0 + qt * 16 + qrow) * HH + chunk * 8] = rd;
        }
        lds_fence();   // WAR before next qt overwrites the bounce
    }
}

// ===========================================================================
// Phase B: merge 16 bf16 partials -> msg; h_new = relu(msg@Wg+b_gcn+h_in(t));
// pred -> out[:,t]; h_proj(t+1) -> hp; h_in(t+1) -> hinT (recomputed, bf16-
// rounding parity; columns stored sigma-permuted).
// 256 blocks x 512 thr (8 waves, 2/SIMD — R6-proven 8-wave GEMM content).
// ===========================================================================
__global__ __launch_bounds__(512) void fuse_kernel(
    const short* __restrict__ OpartB, const float* __restrict__ lpart,
    short* __restrict__ hp, short* __restrict__ hinT,
    const short* __restrict__ WgT, const short* __restrict__ WpT,
    const float* __restrict__ b_gcn, const float* __restrict__ b_proj,
    const float* __restrict__ W_out, const float* __restrict__ b_out,
    const float* __restrict__ x_seq, const float* __restrict__ m_seq,
    const float* __restrict__ W_in,  const float* __restrict__ b_in,
    float* __restrict__ out, int t)
{
    __shared__ __align__(16) short msgb[16 * 136];
    __shared__ __align__(16) short hnb[16 * 136];
    __shared__ __align__(16) short hintb[128 * 16];
    __shared__ float larr[16];
    __shared__ float ppd[8 * 16];

    const int tid = threadIdx.x;
    const int wave = tid >> 6, lane = tid & 63;
    const int ln = lane & 15, g = lane >> 4;
    const int qb = blockIdx.x * 16;

    if (tid < 16) {
        float l = 0.f;
        #pragma unroll
        for (int sp = 0; sp < SPLITS; ++sp) l += lpart[sp * NN + qb + tid];
        larr[tid] = 1.0f / l;
    }
    __syncthreads();

    // merge 16 bf16 partials -> msg (256 thr path, proven)
    if (tid < 256) {
        const int q = tid >> 4, c8 = (tid & 15) * 8;
        float s[8] = {0.f, 0.f, 0.f, 0.f, 0.f, 0.f, 0.f, 0.f};
        #pragma unroll
        for (int sp = 0; sp < SPLITS; ++sp) {
            const short8 v = *(const short8*)&OpartB[((size_t)sp * NN + qb + q) * HH + c8];
            #pragma unroll
            for (int k = 0; k < 8; ++k) s[k] += b2f(v[k]);
        }
        const float inv = larr[q];
        short* mp = &msgb[q * 136 + c8];
        #pragma unroll
        for (int k = 0; k < 8; ++k) mp[k] = f2b(s[k] * inv);
    }
    __syncthreads();

    // GEMM1 (8 waves, nt = wave): h_new = relu(msg@Wg + b_gcn + h_in(t))
    {
        short8 af[4];
        #pragma unroll
        for (int kc = 0; kc < 4; ++kc)
            af[kc] = *(const short8*)&msgb[ln * 136 + kc * 32 + g * 8];
        f32x4 c = {};
        #pragma unroll
        for (int kc = 0; kc < 4; ++kc)
            c = MFMA(af[kc], *(const short8*)&WgT[(wave * 16 + ln) * HH + kc * 32 + g * 8], c);
        const int j = wave * 16 + ln;
        const float bg = b_gcn[j], wo = W_out[j];
        const float wj0 = W_in[j], wj1 = W_in[HH + j], bj = b_in[j];
        float pr[4];
        #pragma unroll
        for (int r = 0; r < 4; ++r) {
            const int q = g * 4 + r;
            float hv = x_seq[(qb + q) * TT + t] * wj0 + m_seq[(qb + q) * TT + t] * wj1 + bj;
            hv = hv > 0.f ? hv : 0.f;
            float v = c[r] + bg + b2f(f2b(hv));
            v = v > 0.f ? v : 0.f;
            hnb[q * 136 + j] = f2b(v);
            pr[r] = v * wo;
        }
        #pragma unroll
        for (int r = 0; r < 4; ++r) {
            float p = pr[r];
            p += __shfl_xor(p, 1); p += __shfl_xor(p, 2);
            p += __shfl_xor(p, 4); p += __shfl_xor(p, 8);
            if (ln == 0) ppd[wave * 16 + g * 4 + r] = p;
        }
    }
    __syncthreads();   // hnb + ppd complete

    if (tid < 16) {
        float s = b_out[0];
        #pragma unroll
        for (int w = 0; w < 8; ++w) s += ppd[w * 16 + tid];
        out[(qb + tid) * TT + t] = s;
    }

    if (t < TT - 1) {
        // GEMM2 (8 waves, nt = wave): h_proj(t+1) = h_new @ W_proj + b_proj
        {
            short8 hf[4];
            #pragma unroll
            for (int kc = 0; kc < 4; ++kc)
                hf[kc] = *(const short8*)&hnb[ln * 136 + kc * 32 + g * 8];
            f32x4 c = {};
            #pragma unroll
            for (int kc = 0; kc < 4; ++kc)
                c = MFMA(hf[kc], *(const short8*)&WpT[(wave * 16 + ln) * HH + kc * 32 + g * 8], c);
            const float bp = b_proj[wave * 16 + ln];
            #pragma unroll
            for (int r = 0; r < 4; ++r)
                hp[(qb + g * 4 + r) * HH + wave * 16 + ln] = f2b(c[r] + bp);
        }

        // h_in(t+1): LDS transpose (256 thr, proven) then sigma-permuted stores
        if (tid < 256) {
            for (int i = tid; i < 16 * HH; i += 256) {
                const int q = i >> 7, j = i & 127;
                float hv = x_seq[(qb + q) * TT + t + 1] * W_in[j]
                         + m_seq[(qb + q) * TT + t + 1] * W_in[HH + j] + b_in[j];
                hv = hv > 0.f ? hv : 0.f;
                hintb[j * 16 + q] = f2b(hv);
            }
        }
        __syncthreads();
        if (tid < 256) {
            for (int c = tid; c < 512; c += 256) {
                const int j = c >> 2, off = (c & 3) * 4;
                const int nb = qb + off;
                const int tcol = (nb & ~31) | (((nb >> 2) & 3) << 3) | (((nb >> 4) & 1) << 2);
                *(u64*)&hinT[(size_t)j * NNP + tcol] = *(const u64*)&hintb[j * 16 + off];
            }
        }
    }
}

// ===========================================================================
extern "C" void kernel_launch(void* const* d_in, const int* in_sizes, int n_in,
                              void* d_out, int out_size, void* d_ws, size_t ws_size,
                              hipStream_t stream) {
    const float* x_seq  = (const float*)d_in[0];
    const float* m_seq  = (const float*)d_in[1];
    const float* W_in   = (const float*)d_in[2];
    const float* b_in   = (const float*)d_in[3];
    const float* W_proj = (const float*)d_in[4];
    const float* b_proj = (const float*)d_in[5];
    const float* W_gcn  = (const float*)d_in[6];
    const float* b_gcn  = (const float*)d_in[7];
    const float* W_out  = (const float*)d_in[8];
    const float* b_out  = (const float*)d_in[9];
    float* out = (float*)d_out;

    // ws carve (~20 MB): hp | hinT(padded) | WgT | WpT | lpart | OpartB
    char* base = (char*)d_ws;
    const size_t MB = 1 << 20;
    short* hp     = (short*)(base + 0 * MB);
    short* hinT   = (short*)(base + 1 * MB);           // 128*4160*2 B
    short* WgT    = (short*)(base + 3 * MB);
    short* WpT    = (short*)(base + 3 * MB + 32768);
    float* lpart  = (float*)(base + 3 * MB + 65536);   // 16*4096*4 = 256 KB
    short* OpartB = (short*)(base + 4 * MB);           // 16*4096*128*2 = 16 MB

    prep_kernel<<<272, 256, 0, stream>>>(x_seq, m_seq, W_in, b_in, W_proj, b_proj,
                                         W_gcn, hp, hinT, WgT, WpT);

    for (int t = 0; t < TT; ++t) {
        attn_kernel<<<(NN / QB) * SPLITS, 256, 0, stream>>>(hp, hinT, OpartB, lpart);
        fuse_kernel<<<NN / 16, 512, 0, stream>>>(OpartB, lpart, hp, hinT,
                                                 WgT, WpT, b_gcn, b_proj, W_out, b_out,
                                                 x_seq, m_seq, W_in, b_in, out, t);
    }
}

// Round 8
// 1982.951 us; speedup vs baseline: 8.6349x; 1.0197x over previous
//
#include <hip/hip_runtime.h>
#include <math.h>

#define NN 4096
#define TT 64
#define HH 128
#define NNP 4160            // hinT row stride (shorts): 8320B kills 8KB L2 set-aliasing
#define SLICE (128 * NNP)   // shorts per hinT time-slice
#define SPLITS 8
#define KPB (NN / SPLITS)   // 512 keys per phase-A block
#define KT 32
#define NTILES (KPB / KT)   // 16
#define QB 64               // q rows per attn block (4 waves x 16)
#define SCALE 0.08838834764831845f   // 1/sqrt(128)
#define CSHIFT 16.0f

typedef __attribute__((ext_vector_type(8))) short short8;
typedef __attribute__((ext_vector_type(4))) float f32x4;
typedef unsigned long long u64;
#define MFMA(a, b, c)   __builtin_amdgcn_mfma_f32_16x16x32_bf16((a), (b), (c), 0, 0, 0)

// ---- bf16 helpers (RNE) ----
__device__ __forceinline__ short f2b(float f) {
    union { float f; unsigned u; } v; v.f = f;
    unsigned r = v.u + 0x7fffu + ((v.u >> 16) & 1u);
    return (short)(r >> 16);
}
__device__ __forceinline__ float b2f(short s) {
    union { unsigned u; float f; } v; v.u = ((unsigned)(unsigned short)s) << 16;
    return v.f;
}
// Wave-local LDS fence: completes ds ops + blocks compiler reordering of
// cross-lane LDS accesses without a block barrier.
__device__ __forceinline__ void lds_fence() {
    __asm__ __volatile__("s_waitcnt lgkmcnt(0)" ::: "memory");
}

// ===========================================================================
// hinT column permutation sigma (within each 32-column group):
//   column c holds node  sigma(c) = (c&4) ? 16 + 4*(c>>3) + (c&3)
//                                         :      4*(c>>3) + (c&3)
// Writers place node kk at column inv_sigma(kk) = ((kk>>2)&3)*8 +
// ((kk>>4)&1)*4 + (kk&3).  After swapped QK^T (st = MFMA(K,Q) -> D[key][q]),
// lane (ln,g) holds the 8 P-values of its query for keys
// {4g..4g+3, 16+4g..16+4g+3} — exactly a 16x16x32 PV A-fragment under sigma
// on the key axis (dot-product axis: permuting BOTH operands is free).
// R3-proven end to end.  l accumulates on the matrix pipe via a B=ones MFMA
// (R5/R6/R7-proven).  cvt_pk inline asm BANNED (NaN R1/2/4).  Coop grid.sync
// BANNED (R6: L2-invalidation -> 23 MB/step HBM re-fetch).
// h_in depends only on inputs -> hinT_all[t] precomputed once in prep.
// ===========================================================================

// ===========================================================================
// prep: once per launch. bf16 weight transposes; hp = b_proj (h0=0);
// hinT_all (64 slices, padded stride NNP, sigma-permuted columns) for ALL t.
// grid: 256 (hp) + 16 (weights) + 4096 (64 t x 64 n-groups).
// ===========================================================================
__global__ __launch_bounds__(256) void prep_kernel(
    const float* __restrict__ x_seq, const float* __restrict__ m_seq,
    const float* __restrict__ W_in,  const float* __restrict__ b_in,
    const float* __restrict__ W_proj,const float* __restrict__ b_proj,
    const float* __restrict__ W_gcn,
    short* __restrict__ hp, short* __restrict__ hinT_all,
    short* __restrict__ WgT, short* __restrict__ WpT)
{
    const int b = blockIdx.x, tid = threadIdx.x;
    if (b < 256) {
        const int n0 = b * 16;
        for (int i = tid; i < 16 * HH; i += 256) {
            const int q = i >> 7, j = i & 127, n = n0 + q;
            hp[n * HH + j] = f2b(b_proj[j]);
        }
    } else if (b < 272) {
        const int wb = b - 256;
        #pragma unroll
        for (int k = 0; k < 4; ++k) {
            const int idx = wb * 1024 + k * 256 + tid;   // = n*128 + kk
            const int n = idx >> 7, kk = idx & 127;
            WgT[idx] = f2b(W_gcn[kk * HH + n]);
            WpT[idx] = f2b(W_proj[kk * HH + n]);
        }
    } else {
        const int u = b - 272;
        const int t = u >> 6, n0 = (u & 63) * 64;
        for (int i = tid; i < 64 * HH; i += 256) {
            const int q = i >> 7, j = i & 127, n = n0 + q;
            float hv = x_seq[n * TT + t] * W_in[j] + m_seq[n * TT + t] * W_in[HH + j] + b_in[j];
            hv = hv > 0.f ? hv : 0.f;
            // col = (n & ~31) | inv_sigma(n & 31)
            const int col = (n & ~31) | (((n >> 2) & 3) << 3) | (((n >> 4) & 1) << 2) | (n & 3);
            hinT_all[(size_t)t * SLICE + (size_t)j * NNP + col] = f2b(hv);
        }
    }
}

// ===========================================================================
// Phase A: attention partials. 512 blocks (64 qg x 8 splits) x 256 thr
// (4 waves) -> up to 3 co-resident blocks/CU (LDS 3x37KB, VGPR-capped via
// __launch_bounds__(256,3)): independent barrier domains keep the
// MFMA/VALU/mem pipes busy across tile-barrier drains (m114 overlap).
// Wave owns ONE q-tile (16 rows) — strict subset of the R3/R7-proven
// 2-q-tile body.  Block stages its 512-key slice via LDS double-buffered
// K/V tiles, ONE barrier/tile.  Swapped QK^T -> in-register f2b softmax ->
// PV via sigma; l on the matrix pipe (ones column).  O partials out bf16
// via the per-wave LDS bounce.  hinT = this step's precomputed slice.
// ===========================================================================
__global__ __launch_bounds__(256, 3) void attn_kernel(
    const short* __restrict__ hp, const short* __restrict__ hinT,
    short* __restrict__ OpartB, float* __restrict__ lpart)
{
    __shared__ __align__(16) char pool[37888];
    short* KtS = (short*)pool;                  // [2][32*136]  17408 B
    short* VtS = (short*)(pool + 17408);        // [2][128*40]  20480 B

    const int tid  = threadIdx.x;
    const int wave = tid >> 6, lane = tid & 63;
    const int ln = lane & 15, g = lane >> 4;
    const int qg = blockIdx.x >> 3, split = blockIdx.x & 7;
    const int q0 = qg * QB + wave * 16;
    const int kbase = split * KPB;

    // staging thread maps (256 threads, 16B/lane coalesced, 2 passes each)
    const int krow = tid >> 4, kcol = (tid & 15) * 8;   // rows 0..15 (+16)
    const int vrow = tid >> 2, vcol = (tid & 3) * 8;    // rows 0..63 (+64)

    // Q fragment (B-operand in swapped QK^T): 1 q-tile, proven layout
    short8 qf[4];
    #pragma unroll
    for (int kc = 0; kc < 4; ++kc)
        qf[kc] = *(const short8*)&hp[(q0 + ln) * HH + kc * 32 + g * 8];

    f32x4 oacc[8] = {};   // O[q = g*4 + r][d = dt*16 + ln]
    f32x4 lacc = {};      // l (ones-column accumulator, matrix pipe)
    short8 vone;
    #pragma unroll
    for (int e = 0; e < 8; ++e) vone[e] = (short)0x3F80;   // bf16 1.0

    short8 ksA0, ksA1, vsA0, vsA1;
    auto load_tile = [&](int kt_) {
        const int kb = kbase + kt_ * KT;
        ksA0 = *(const short8*)&hp  [(kb + krow) * HH + kcol];
        ksA1 = *(const short8*)&hp  [(kb + krow + 16) * HH + kcol];
        vsA0 = *(const short8*)&hinT[(size_t)vrow * NNP + kb + vcol];
        vsA1 = *(const short8*)&hinT[(size_t)(vrow + 64) * NNP + kb + vcol];
    };
    auto store_tile = [&](int b) {
        *(short8*)&KtS[b * 4352 + krow * 136 + kcol]        = ksA0;
        *(short8*)&KtS[b * 4352 + (krow + 16) * 136 + kcol] = ksA1;
        *(short8*)&VtS[b * 5120 + vrow * 40 + vcol]         = vsA0;
        *(short8*)&VtS[b * 5120 + (vrow + 64) * 40 + vcol]  = vsA1;
    };

    load_tile(0);
    store_tile(0);

    for (int kt = 0; kt < NTILES; ++kt) {
        const int b = kt & 1;
        __syncthreads();   // buf b staged; prev iter's frag reads drained (WAR)

        short8 kf[2][4], vf[8];
        #pragma unroll
        for (int kt2 = 0; kt2 < 2; ++kt2)
            #pragma unroll
            for (int kc = 0; kc < 4; ++kc)
                kf[kt2][kc] = *(const short8*)&KtS[b * 4352 + (kt2 * 16 + ln) * 136 + kc * 32 + g * 8];
        #pragma unroll
        for (int dt = 0; dt < 8; ++dt)
            vf[dt] = *(const short8*)&VtS[b * 5120 + (dt * 16 + ln) * 40 + g * 8];

        if (kt + 1 < NTILES) load_tile(kt + 1);   // global -> regs, overlaps compute

        // swapped scores: st[kt2][r] = S[key = kt2*16+g*4+r][q = q0+ln]
        f32x4 st[2] = {};
        __builtin_amdgcn_s_setprio(1);
        #pragma unroll
        for (int kt2 = 0; kt2 < 2; ++kt2)
            #pragma unroll
            for (int kc = 0; kc < 4; ++kc)
                st[kt2] = MFMA(kf[kt2][kc], qf[kc], st[kt2]);
        __builtin_amdgcn_s_setprio(0);

        // fixed-shift softmax numerators -> bf16 A-fragment (proven order)
        short8 pa;
        #pragma unroll
        for (int e = 0; e < 8; ++e) {
            const float s = (e < 4) ? st[0][e] : st[1][e - 4];
            pa[e] = f2b(__expf(s * SCALE - CSHIFT));
        }

        if (kt + 1 < NTILES) store_tile(b ^ 1);

        // PV (+ l via ones column): pa is the A-fragment in slot space
        __builtin_amdgcn_s_setprio(1);
        #pragma unroll
        for (int dt = 0; dt < 8; ++dt)
            oacc[dt] = MFMA(pa, vf[dt], oacc[dt]);
        lacc = MFMA(pa, vone, lacc);
        __builtin_amdgcn_s_setprio(0);
    }

    __syncthreads();   // all waves' LDS frag reads done -> pool reusable as bounce

    // l: ones-column output is col-replicated; row q = g*4 + r (proven D map)
    if (ln == 0) {
        #pragma unroll
        for (int r = 0; r < 4; ++r)
            lpart[split * NN + q0 + g * 4 + r] = lacc[r];
    }

    // O partials -> bf16 via per-wave LDS bounce (coalesced 16B/lane stores)
    short* bounce = (short*)pool + wave * 2048;   // 4KB/wave in dead Kt/Vt
    #pragma unroll
    for (int dt = 0; dt < 8; ++dt)
        #pragma unroll
        for (int r = 0; r < 4; ++r)
            bounce[(g * 4 + r) * 128 + dt * 16 + ln] = f2b(oacc[dt][r]);
    lds_fence();   // RAW: cross-lane bounce writes before row reads
    #pragma unroll
    for (int sub = 0; sub < 4; ++sub) {
        const int qrow = sub * 4 + (lane >> 4), chunk = lane & 15;
        const short8 rd = *(const short8*)&bounce[qrow * 128 + chunk * 8];
        *(short8*)&OpartB[((size_t)split * NN + q0 + qrow) * HH + chunk * 8] = rd;
    }
}

// ===========================================================================
// Phase B: merge 8 bf16 partials -> msg; h_new = relu(msg@Wg+b_gcn+h_in(t));
// pred -> out[:,t]; h_proj(t+1) -> hp.  (h_in now precomputed in prep.)
// 256 blocks x 512 thr (8 waves, 2/SIMD — R6/R7-proven 8-wave GEMM content).
// ===========================================================================
__global__ __launch_bounds__(512) void fuse_kernel(
    const short* __restrict__ OpartB, const float* __restrict__ lpart,
    short* __restrict__ hp,
    const short* __restrict__ WgT, const short* __restrict__ WpT,
    const float* __restrict__ b_gcn, const float* __restrict__ b_proj,
    const float* __restrict__ W_out, const float* __restrict__ b_out,
    const float* __restrict__ x_seq, const float* __restrict__ m_seq,
    const float* __restrict__ W_in,  const float* __restrict__ b_in,
    float* __restrict__ out, int t)
{
    __shared__ __align__(16) short msgb[16 * 136];
    __shared__ __align__(16) short hnb[16 * 136];
    __shared__ float larr[16];
    __shared__ float ppd[8 * 16];

    const int tid = threadIdx.x;
    const int wave = tid >> 6, lane = tid & 63;
    const int ln = lane & 15, g = lane >> 4;
    const int qb = blockIdx.x * 16;

    if (tid < 16) {
        float l = 0.f;
        #pragma unroll
        for (int sp = 0; sp < SPLITS; ++sp) l += lpart[sp * NN + qb + tid];
        larr[tid] = 1.0f / l;
    }
    __syncthreads();

    // merge 8 bf16 partials -> msg (256 thr path, proven)
    if (tid < 256) {
        const int q = tid >> 4, c8 = (tid & 15) * 8;
        float s[8] = {0.f, 0.f, 0.f, 0.f, 0.f, 0.f, 0.f, 0.f};
        #pragma unroll
        for (int sp = 0; sp < SPLITS; ++sp) {
            const short8 v = *(const short8*)&OpartB[((size_t)sp * NN + qb + q) * HH + c8];
            #pragma unroll
            for (int k = 0; k < 8; ++k) s[k] += b2f(v[k]);
        }
        const float inv = larr[q];
        short* mp = &msgb[q * 136 + c8];
        #pragma unroll
        for (int k = 0; k < 8; ++k) mp[k] = f2b(s[k] * inv);
    }
    __syncthreads();

    // GEMM1 (8 waves, nt = wave): h_new = relu(msg@Wg + b_gcn + h_in(t))
    {
        short8 af[4];
        #pragma unroll
        for (int kc = 0; kc < 4; ++kc)
            af[kc] = *(const short8*)&msgb[ln * 136 + kc * 32 + g * 8];
        f32x4 c = {};
        #pragma unroll
        for (int kc = 0; kc < 4; ++kc)
            c = MFMA(af[kc], *(const short8*)&WgT[(wave * 16 + ln) * HH + kc * 32 + g * 8], c);
        const int j = wave * 16 + ln;
        const float bg = b_gcn[j], wo = W_out[j];
        const float wj0 = W_in[j], wj1 = W_in[HH + j], bj = b_in[j];
        float pr[4];
        #pragma unroll
        for (int r = 0; r < 4; ++r) {
            const int q = g * 4 + r;
            float hv = x_seq[(qb + q) * TT + t] * wj0 + m_seq[(qb + q) * TT + t] * wj1 + bj;
            hv = hv > 0.f ? hv : 0.f;
            float v = c[r] + bg + b2f(f2b(hv));
            v = v > 0.f ? v : 0.f;
            hnb[q * 136 + j] = f2b(v);
            pr[r] = v * wo;
        }
        #pragma unroll
        for (int r = 0; r < 4; ++r) {
            float p = pr[r];
            p += __shfl_xor(p, 1); p += __shfl_xor(p, 2);
            p += __shfl_xor(p, 4); p += __shfl_xor(p, 8);
            if (ln == 0) ppd[wave * 16 + g * 4 + r] = p;
        }
    }
    __syncthreads();   // hnb + ppd complete

    if (tid < 16) {
        float s = b_out[0];
        #pragma unroll
        for (int w = 0; w < 8; ++w) s += ppd[w * 16 + tid];
        out[(qb + tid) * TT + t] = s;
    }

    if (t < TT - 1) {
        // GEMM2 (8 waves, nt = wave): h_proj(t+1) = h_new @ W_proj + b_proj
        short8 hf[4];
        #pragma unroll
        for (int kc = 0; kc < 4; ++kc)
            hf[kc] = *(const short8*)&hnb[ln * 136 + kc * 32 + g * 8];
        f32x4 c = {};
        #pragma unroll
        for (int kc = 0; kc < 4; ++kc)
            c = MFMA(hf[kc], *(const short8*)&WpT[(wave * 16 + ln) * HH + kc * 32 + g * 8], c);
        const float bp = b_proj[wave * 16 + ln];
        #pragma unroll
        for (int r = 0; r < 4; ++r)
            hp[(qb + g * 4 + r) * HH + wave * 16 + ln] = f2b(c[r] + bp);
    }
}

// ===========================================================================
extern "C" void kernel_launch(void* const* d_in, const int* in_sizes, int n_in,
                              void* d_out, int out_size, void* d_ws, size_t ws_size,
                              hipStream_t stream) {
    const float* x_seq  = (const float*)d_in[0];
    const float* m_seq  = (const float*)d_in[1];
    const float* W_in   = (const float*)d_in[2];
    const float* b_in   = (const float*)d_in[3];
    const float* W_proj = (const float*)d_in[4];
    const float* b_proj = (const float*)d_in[5];
    const float* W_gcn  = (const float*)d_in[6];
    const float* b_gcn  = (const float*)d_in[7];
    const float* W_out  = (const float*)d_in[8];
    const float* b_out  = (const float*)d_in[9];
    float* out = (float*)d_out;

    // ws carve (~100 MB of the 256 MiB workspace):
    //   hp @0 | WgT/WpT/lpart @3MB | OpartB @4MB (8MB) | hinT_all @32MB (67MB)
    char* base = (char*)d_ws;
    const size_t MB = 1 << 20;
    short* hp       = (short*)(base + 0 * MB);
    short* WgT      = (short*)(base + 3 * MB);
    short* WpT      = (short*)(base + 3 * MB + 32768);
    float* lpart    = (float*)(base + 3 * MB + 65536);   // 8*4096*4 = 128 KB
    short* OpartB   = (short*)(base + 4 * MB);           // 8*4096*128*2 = 8 MB
    short* hinT_all = (short*)(base + 32 * MB);          // 64*128*4160*2 ≈ 67 MB

    prep_kernel<<<272 + 64 * 64, 256, 0, stream>>>(x_seq, m_seq, W_in, b_in,
                                                   W_proj, b_proj, W_gcn,
                                                   hp, hinT_all, WgT, WpT);

    for (int t = 0; t < TT; ++t) {
        const short* hinT_t = hinT_all + (size_t)t * SLICE;
        attn_kernel<<<(NN / QB) * SPLITS, 256, 0, stream>>>(hp, hinT_t, OpartB, lpart);
        fuse_kernel<<<NN / 16, 512, 0, stream>>>(OpartB, lpart, hp,
                                                 WgT, WpT, b_gcn, b_proj, W_out, b_out,
                                                 x_seq, m_seq, W_in, b_in, out, t);
    }
}

// Round 9
// 1893.544 us; speedup vs baseline: 9.0426x; 1.0472x over previous
//
#include <hip/hip_runtime.h>
#include <math.h>

#define NN 4096
#define TT 64
#define HH 128
#define NNP 4160            // hinT row stride (shorts): 8320B kills 8KB L2 set-aliasing
#define SLICE (128 * NNP)   // shorts per hinT time-slice
#define SPLITS 8
#define KPB (NN / SPLITS)   // 512 keys per phase-A block
#define KT 32
#define NTILES (KPB / KT)   // 16
#define QB 64               // q rows per attn block (4 waves x 16)
#define SCALE 0.08838834764831845f   // 1/sqrt(128)
#define CSHIFT 16.0f

typedef __attribute__((ext_vector_type(8))) short short8;
typedef __attribute__((ext_vector_type(4))) float f32x4;
typedef unsigned long long u64;
#define MFMA(a, b, c)   __builtin_amdgcn_mfma_f32_16x16x32_bf16((a), (b), (c), 0, 0, 0)

// ---- bf16 helpers (RNE) ----
__device__ __forceinline__ short f2b(float f) {
    union { float f; unsigned u; } v; v.f = f;
    unsigned r = v.u + 0x7fffu + ((v.u >> 16) & 1u);
    return (short)(r >> 16);
}
__device__ __forceinline__ float b2f(short s) {
    union { unsigned u; float f; } v; v.u = ((unsigned)(unsigned short)s) << 16;
    return v.f;
}
// Wave-local LDS fence: completes ds ops + blocks compiler reordering of
// cross-lane LDS accesses without a block barrier.
__device__ __forceinline__ void lds_fence() {
    __asm__ __volatile__("s_waitcnt lgkmcnt(0)" ::: "memory");
}

// ===========================================================================
// hinT column permutation sigma (within each 32-column group):
//   column c holds node  sigma(c) = (c&4) ? 16 + 4*(c>>3) + (c&3)
//                                         :      4*(c>>3) + (c&3)
// Writers place node kk at column inv_sigma(kk) = ((kk>>2)&3)*8 +
// ((kk>>4)&1)*4 + (kk&3)  (maps aligned-4 node chunks -> aligned-4 columns).
// After swapped QK^T (st = MFMA(K,Q) -> D[key][q]), lane (ln,g) holds the 8
// P-values of its query for keys {4g..4g+3, 16+4g..16+4g+3} — exactly a
// 16x16x32 PV A-fragment under sigma on the key axis (dot-product axis:
// permuting BOTH operands is free).  R3-proven end to end.  l accumulates on
// the matrix pipe via a B=ones MFMA (R5-R8 proven).  cvt_pk inline asm
// BANNED (NaN R1/2/4).  Coop grid.sync BANNED (R6: L2 invalidation).
// R8 lesson: prep's per-lane strided 2B hinT stores caused 2.5x write
// amplification (170 MB vs 69 MB useful, 161 us) -> LDS-transpose + 8B
// coalesced chunk stores (the proven fuse pattern) here.
// ===========================================================================

// ===========================================================================
// prep: once per launch. bf16 weight transposes; hp = b_proj (h0=0);
// hinT_all (64 slices, padded stride NNP, sigma-permuted columns) for ALL t.
// grid: 256 (hp) + 16 (weights) + 4096 (64 t x 64 n-groups, LDS-transposed).
// ===========================================================================
__global__ __launch_bounds__(256) void prep_kernel(
    const float* __restrict__ x_seq, const float* __restrict__ m_seq,
    const float* __restrict__ W_in,  const float* __restrict__ b_in,
    const float* __restrict__ W_proj,const float* __restrict__ b_proj,
    const float* __restrict__ W_gcn,
    short* __restrict__ hp, short* __restrict__ hinT_all,
    short* __restrict__ WgT, short* __restrict__ WpT)
{
    __shared__ __align__(16) short hb[128 * 64];   // [j][q] 16 KB
    const int b = blockIdx.x, tid = threadIdx.x;
    if (b < 256) {
        const int n0 = b * 16;
        for (int i = tid; i < 16 * HH; i += 256) {
            const int q = i >> 7, j = i & 127, n = n0 + q;
            hp[n * HH + j] = f2b(b_proj[j]);
        }
    } else if (b < 272) {
        const int wb = b - 256;
        #pragma unroll
        for (int k = 0; k < 4; ++k) {
            const int idx = wb * 1024 + k * 256 + tid;   // = n*128 + kk
            const int n = idx >> 7, kk = idx & 127;
            WgT[idx] = f2b(W_gcn[kk * HH + n]);
            WpT[idx] = f2b(W_proj[kk * HH + n]);
        }
    } else {
        const int u = b - 272;
        const int t = u >> 6, n0 = (u & 63) * 64;
        // compute h_in for 64 nodes x 128 features into LDS (transposed)
        for (int i = tid; i < 64 * HH; i += 256) {
            const int q = i >> 7, j = i & 127, n = n0 + q;
            float hv = x_seq[n * TT + t] * W_in[j] + m_seq[n * TT + t] * W_in[HH + j] + b_in[j];
            hv = hv > 0.f ? hv : 0.f;
            hb[j * 64 + q] = f2b(hv);
        }
        __syncthreads();
        // coalesced sigma-permuted stores: 8B chunks, 16 lanes = 128B per row
        short* dst = hinT_all + (size_t)t * SLICE;
        for (int c = tid; c < 128 * 16; c += 256) {
            const int j = c >> 4, off = (c & 15) * 4;
            const int nb = n0 + off;
            const int tcol = (nb & ~31) | (((nb >> 2) & 3) << 3) | (((nb >> 4) & 1) << 2);
            *(u64*)&dst[(size_t)j * NNP + tcol] = *(const u64*)&hb[j * 64 + off];
        }
    }
}

// ===========================================================================
// Phase A: attention partials. 512 blocks (64 qg x 8 splits) x 256 thr
// (4 waves) -> up to 3 co-resident blocks/CU (LDS 3x37KB, VGPR-capped via
// __launch_bounds__(256,3)): independent barrier domains keep the
// MFMA/VALU/mem pipes busy across tile-barrier drains (m114 overlap).
// Wave owns ONE q-tile (16 rows) — strict subset of the R3/R7-proven
// 2-q-tile body.  Block stages its 512-key slice via LDS double-buffered
// K/V tiles, ONE barrier/tile.  Swapped QK^T -> in-register f2b softmax ->
// PV via sigma; l on the matrix pipe (ones column).  O partials out bf16
// via the per-wave LDS bounce.  hinT = this step's precomputed slice.
// ===========================================================================
__global__ __launch_bounds__(256, 3) void attn_kernel(
    const short* __restrict__ hp, const short* __restrict__ hinT,
    short* __restrict__ OpartB, float* __restrict__ lpart)
{
    __shared__ __align__(16) char pool[37888];
    short* KtS = (short*)pool;                  // [2][32*136]  17408 B
    short* VtS = (short*)(pool + 17408);        // [2][128*40]  20480 B

    const int tid  = threadIdx.x;
    const int wave = tid >> 6, lane = tid & 63;
    const int ln = lane & 15, g = lane >> 4;
    const int qg = blockIdx.x >> 3, split = blockIdx.x & 7;
    const int q0 = qg * QB + wave * 16;
    const int kbase = split * KPB;

    // staging thread maps (256 threads, 16B/lane coalesced, 2 passes each)
    const int krow = tid >> 4, kcol = (tid & 15) * 8;   // rows 0..15 (+16)
    const int vrow = tid >> 2, vcol = (tid & 3) * 8;    // rows 0..63 (+64)

    // Q fragment (B-operand in swapped QK^T): 1 q-tile, proven layout
    short8 qf[4];
    #pragma unroll
    for (int kc = 0; kc < 4; ++kc)
        qf[kc] = *(const short8*)&hp[(q0 + ln) * HH + kc * 32 + g * 8];

    f32x4 oacc[8] = {};   // O[q = g*4 + r][d = dt*16 + ln]
    f32x4 lacc = {};      // l (ones-column accumulator, matrix pipe)
    short8 vone;
    #pragma unroll
    for (int e = 0; e < 8; ++e) vone[e] = (short)0x3F80;   // bf16 1.0

    short8 ksA0, ksA1, vsA0, vsA1;
    auto load_tile = [&](int kt_) {
        const int kb = kbase + kt_ * KT;
        ksA0 = *(const short8*)&hp  [(kb + krow) * HH + kcol];
        ksA1 = *(const short8*)&hp  [(kb + krow + 16) * HH + kcol];
        vsA0 = *(const short8*)&hinT[(size_t)vrow * NNP + kb + vcol];
        vsA1 = *(const short8*)&hinT[(size_t)(vrow + 64) * NNP + kb + vcol];
    };
    auto store_tile = [&](int b) {
        *(short8*)&KtS[b * 4352 + krow * 136 + kcol]        = ksA0;
        *(short8*)&KtS[b * 4352 + (krow + 16) * 136 + kcol] = ksA1;
        *(short8*)&VtS[b * 5120 + vrow * 40 + vcol]         = vsA0;
        *(short8*)&VtS[b * 5120 + (vrow + 64) * 40 + vcol]  = vsA1;
    };

    load_tile(0);
    store_tile(0);

    for (int kt = 0; kt < NTILES; ++kt) {
        const int b = kt & 1;
        __syncthreads();   // buf b staged; prev iter's frag reads drained (WAR)

        short8 kf[2][4], vf[8];
        #pragma unroll
        for (int kt2 = 0; kt2 < 2; ++kt2)
            #pragma unroll
            for (int kc = 0; kc < 4; ++kc)
                kf[kt2][kc] = *(const short8*)&KtS[b * 4352 + (kt2 * 16 + ln) * 136 + kc * 32 + g * 8];
        #pragma unroll
        for (int dt = 0; dt < 8; ++dt)
            vf[dt] = *(const short8*)&VtS[b * 5120 + (dt * 16 + ln) * 40 + g * 8];

        if (kt + 1 < NTILES) load_tile(kt + 1);   // global -> regs, overlaps compute

        // swapped scores: st[kt2][r] = S[key = kt2*16+g*4+r][q = q0+ln]
        f32x4 st[2] = {};
        __builtin_amdgcn_s_setprio(1);
        #pragma unroll
        for (int kt2 = 0; kt2 < 2; ++kt2)
            #pragma unroll
            for (int kc = 0; kc < 4; ++kc)
                st[kt2] = MFMA(kf[kt2][kc], qf[kc], st[kt2]);
        __builtin_amdgcn_s_setprio(0);

        // fixed-shift softmax numerators -> bf16 A-fragment (proven order)
        short8 pa;
        #pragma unroll
        for (int e = 0; e < 8; ++e) {
            const float s = (e < 4) ? st[0][e] : st[1][e - 4];
            pa[e] = f2b(__expf(s * SCALE - CSHIFT));
        }

        if (kt + 1 < NTILES) store_tile(b ^ 1);

        // PV (+ l via ones column): pa is the A-fragment in slot space
        __builtin_amdgcn_s_setprio(1);
        #pragma unroll
        for (int dt = 0; dt < 8; ++dt)
            oacc[dt] = MFMA(pa, vf[dt], oacc[dt]);
        lacc = MFMA(pa, vone, lacc);
        __builtin_amdgcn_s_setprio(0);
    }

    __syncthreads();   // all waves' LDS frag reads done -> pool reusable as bounce

    // l: ones-column output is col-replicated; row q = g*4 + r (proven D map)
    if (ln == 0) {
        #pragma unroll
        for (int r = 0; r < 4; ++r)
            lpart[split * NN + q0 + g * 4 + r] = lacc[r];
    }

    // O partials -> bf16 via per-wave LDS bounce (coalesced 16B/lane stores)
    short* bounce = (short*)pool + wave * 2048;   // 4KB/wave in dead Kt/Vt
    #pragma unroll
    for (int dt = 0; dt < 8; ++dt)
        #pragma unroll
        for (int r = 0; r < 4; ++r)
            bounce[(g * 4 + r) * 128 + dt * 16 + ln] = f2b(oacc[dt][r]);
    lds_fence();   // RAW: cross-lane bounce writes before row reads
    #pragma unroll
    for (int sub = 0; sub < 4; ++sub) {
        const int qrow = sub * 4 + (lane >> 4), chunk = lane & 15;
        const short8 rd = *(const short8*)&bounce[qrow * 128 + chunk * 8];
        *(short8*)&OpartB[((size_t)split * NN + q0 + qrow) * HH + chunk * 8] = rd;
    }
}

// ===========================================================================
// Phase B: merge 8 bf16 partials -> msg; h_new = relu(msg@Wg+b_gcn+h_in(t));
// pred -> out[:,t]; h_proj(t+1) -> hp.  (h_in precomputed in prep.)
// 256 blocks x 512 thr (8 waves, 2/SIMD — R6/R7-proven 8-wave GEMM content).
// ===========================================================================
__global__ __launch_bounds__(512) void fuse_kernel(
    const short* __restrict__ OpartB, const float* __restrict__ lpart,
    short* __restrict__ hp,
    const short* __restrict__ WgT, const short* __restrict__ WpT,
    const float* __restrict__ b_gcn, const float* __restrict__ b_proj,
    const float* __restrict__ W_out, const float* __restrict__ b_out,
    const float* __restrict__ x_seq, const float* __restrict__ m_seq,
    const float* __restrict__ W_in,  const float* __restrict__ b_in,
    float* __restrict__ out, int t)
{
    __shared__ __align__(16) short msgb[16 * 136];
    __shared__ __align__(16) short hnb[16 * 136];
    __shared__ float larr[16];
    __shared__ float ppd[8 * 16];

    const int tid = threadIdx.x;
    const int wave = tid >> 6, lane = tid & 63;
    const int ln = lane & 15, g = lane >> 4;
    const int qb = blockIdx.x * 16;

    if (tid < 16) {
        float l = 0.f;
        #pragma unroll
        for (int sp = 0; sp < SPLITS; ++sp) l += lpart[sp * NN + qb + tid];
        larr[tid] = 1.0f / l;
    }
    __syncthreads();

    // merge 8 bf16 partials -> msg (256 thr path, proven)
    if (tid < 256) {
        const int q = tid >> 4, c8 = (tid & 15) * 8;
        float s[8] = {0.f, 0.f, 0.f, 0.f, 0.f, 0.f, 0.f, 0.f};
        #pragma unroll
        for (int sp = 0; sp < SPLITS; ++sp) {
            const short8 v = *(const short8*)&OpartB[((size_t)sp * NN + qb + q) * HH + c8];
            #pragma unroll
            for (int k = 0; k < 8; ++k) s[k] += b2f(v[k]);
        }
        const float inv = larr[q];
        short* mp = &msgb[q * 136 + c8];
        #pragma unroll
        for (int k = 0; k < 8; ++k) mp[k] = f2b(s[k] * inv);
    }
    __syncthreads();

    // GEMM1 (8 waves, nt = wave): h_new = relu(msg@Wg + b_gcn + h_in(t))
    {
        short8 af[4];
        #pragma unroll
        for (int kc = 0; kc < 4; ++kc)
            af[kc] = *(const short8*)&msgb[ln * 136 + kc * 32 + g * 8];
        f32x4 c = {};
        #pragma unroll
        for (int kc = 0; kc < 4; ++kc)
            c = MFMA(af[kc], *(const short8*)&WgT[(wave * 16 + ln) * HH + kc * 32 + g * 8], c);
        const int j = wave * 16 + ln;
        const float bg = b_gcn[j], wo = W_out[j];
        const float wj0 = W_in[j], wj1 = W_in[HH + j], bj = b_in[j];
        float pr[4];
        #pragma unroll
        for (int r = 0; r < 4; ++r) {
            const int q = g * 4 + r;
            float hv = x_seq[(qb + q) * TT + t] * wj0 + m_seq[(qb + q) * TT + t] * wj1 + bj;
            hv = hv > 0.f ? hv : 0.f;
            float v = c[r] + bg + b2f(f2b(hv));
            v = v > 0.f ? v : 0.f;
            hnb[q * 136 + j] = f2b(v);
            pr[r] = v * wo;
        }
        #pragma unroll
        for (int r = 0; r < 4; ++r) {
            float p = pr[r];
            p += __shfl_xor(p, 1); p += __shfl_xor(p, 2);
            p += __shfl_xor(p, 4); p += __shfl_xor(p, 8);
            if (ln == 0) ppd[wave * 16 + g * 4 + r] = p;
        }
    }
    __syncthreads();   // hnb + ppd complete

    if (tid < 16) {
        float s = b_out[0];
        #pragma unroll
        for (int w = 0; w < 8; ++w) s += ppd[w * 16 + tid];
        out[(qb + tid) * TT + t] = s;
    }

    if (t < TT - 1) {
        // GEMM2 (8 waves, nt = wave): h_proj(t+1) = h_new @ W_proj + b_proj
        short8 hf[4];
        #pragma unroll
        for (int kc = 0; kc < 4; ++kc)
            hf[kc] = *(const short8*)&hnb[ln * 136 + kc * 32 + g * 8];
        f32x4 c = {};
        #pragma unroll
        for (int kc = 0; kc < 4; ++kc)
            c = MFMA(hf[kc], *(const short8*)&WpT[(wave * 16 + ln) * HH + kc * 32 + g * 8], c);
        const float bp = b_proj[wave * 16 + ln];
        #pragma unroll
        for (int r = 0; r < 4; ++r)
            hp[(qb + g * 4 + r) * HH + wave * 16 + ln] = f2b(c[r] + bp);
    }
}

// ===========================================================================
extern "C" void kernel_launch(void* const* d_in, const int* in_sizes, int n_in,
                              void* d_out, int out_size, void* d_ws, size_t ws_size,
                              hipStream_t stream) {
    const float* x_seq  = (const float*)d_in[0];
    const float* m_seq  = (const float*)d_in[1];
    const float* W_in   = (const float*)d_in[2];
    const float* b_in   = (const float*)d_in[3];
    const float* W_proj = (const float*)d_in[4];
    const float* b_proj = (const float*)d_in[5];
    const float* W_gcn  = (const float*)d_in[6];
    const float* b_gcn  = (const float*)d_in[7];
    const float* W_out  = (const float*)d_in[8];
    const float* b_out  = (const float*)d_in[9];
    float* out = (float*)d_out;

    // ws carve (~100 MB of the 256 MiB workspace):
    //   hp @0 | WgT/WpT/lpart @3MB | OpartB @4MB (8MB) | hinT_all @32MB (67MB)
    char* base = (char*)d_ws;
    const size_t MB = 1 << 20;
    short* hp       = (short*)(base + 0 * MB);
    short* WgT      = (short*)(base + 3 * MB);
    short* WpT      = (short*)(base + 3 * MB + 32768);
    float* lpart    = (float*)(base + 3 * MB + 65536);   // 8*4096*4 = 128 KB
    short* OpartB   = (short*)(base + 4 * MB);           // 8*4096*128*2 = 8 MB
    short* hinT_all = (short*)(base + 32 * MB);          // 64*128*4160*2 ≈ 67 MB

    prep_kernel<<<272 + 64 * 64, 256, 0, stream>>>(x_seq, m_seq, W_in, b_in,
                                                   W_proj, b_proj, W_gcn,
                                                   hp, hinT_all, WgT, WpT);

    for (int t = 0; t < TT; ++t) {
        const short* hinT_t = hinT_all + (size_t)t * SLICE;
        attn_kernel<<<(NN / QB) * SPLITS, 256, 0, stream>>>(hp, hinT_t, OpartB, lpart);
        fuse_kernel<<<NN / 16, 512, 0, stream>>>(OpartB, lpart, hp,
                                                 WgT, WpT, b_gcn, b_proj, W_out, b_out,
                                                 x_seq, m_seq, W_in, b_in, out, t);
    }
}

// Round 10
// 1613.282 us; speedup vs baseline: 10.6135x; 1.1737x over previous
//
#include <hip/hip_runtime.h>
#include <math.h>

#define NN 4096
#define TT 64
#define HH 128
#define NNP 4160            // hinT row stride (shorts): 8320B kills 8KB L2 set-aliasing
#define SLICE (128 * NNP)   // shorts per hinT time-slice
#define SPLITS 8
#define KPB (NN / SPLITS)   // 512 keys per phase-A block
#define KT 32
#define NTILES (KPB / KT)   // 16
#define QB 64               // q rows per attn block (4 waves x 16)
#define SCALE 0.08838834764831845f   // 1/sqrt(128)
#define CSHIFT 16.0f

typedef __attribute__((ext_vector_type(8))) short short8;
typedef __attribute__((ext_vector_type(4))) float f32x4;
typedef unsigned long long u64;
#define MFMA(a, b, c)   __builtin_amdgcn_mfma_f32_16x16x32_bf16((a), (b), (c), 0, 0, 0)

// ---- bf16 helpers (RNE) ----
__device__ __forceinline__ short f2b(float f) {
    union { float f; unsigned u; } v; v.f = f;
    unsigned r = v.u + 0x7fffu + ((v.u >> 16) & 1u);
    return (short)(r >> 16);
}
__device__ __forceinline__ float b2f(short s) {
    union { unsigned u; float f; } v; v.u = ((unsigned)(unsigned short)s) << 16;
    return v.f;
}
// Wave-local LDS fence: completes ds ops + blocks compiler reordering of
// cross-lane LDS accesses without a block barrier.
__device__ __forceinline__ void lds_fence() {
    __asm__ __volatile__("s_waitcnt lgkmcnt(0)" ::: "memory");
}

// ===========================================================================
// hinT column permutation sigma (within each 32-column group):
//   column c holds node  sigma(c) = (c&4) ? 16 + 4*(c>>3) + (c&3)
//                                         :      4*(c>>3) + (c&3)
// Writers place node kk at column inv_sigma(kk) = ((kk>>2)&3)*8 +
// ((kk>>4)&1)*4 + (kk&3)  (maps aligned-4 node chunks -> aligned-4 columns).
// After swapped QK^T (st = MFMA(K,Q) -> D[key][q]), lane (ln,g) holds the 8
// P-values of its query for keys {4g..4g+3, 16+4g..16+4g+3} — exactly a
// 16x16x32 PV A-fragment under sigma on the key axis (dot-product axis:
// permuting BOTH operands is free).  R3-proven end to end.  l accumulates on
// the matrix pipe via a B=ones MFMA (R5-R8 proven).  cvt_pk inline asm
// BANNED (NaN R1/2/4).  Coop grid.sync BANNED (R6: L2 invalidation).
// R9 lesson: prep's LDS transpose at stride 64 shorts was a 32-way write
// bank conflict (3.25e7 conflict cycles = ~53 us) -> stride 66 (write bank
// = (j+q/2)%32, read via 2xu32) makes both sides conflict-free.
// XCD locality (R10): attn bid = split*64+qg and the matching fuse bijection
// put all 8 split-producers of a qg AND its consumer on XCD qg%8, so the
// OpartB/lpart round trip stays in one XCD's L2 instead of HBM.
// ===========================================================================

// ===========================================================================
// prep: once per launch. bf16 weight transposes; hp = b_proj (h0=0);
// hinT_all (64 slices, padded stride NNP, sigma-permuted columns) for ALL t.
// grid: 256 (hp) + 16 (weights) + 4096 (64 t x 64 n-groups, LDS-transposed).
// ===========================================================================
__global__ __launch_bounds__(256) void prep_kernel(
    const float* __restrict__ x_seq, const float* __restrict__ m_seq,
    const float* __restrict__ W_in,  const float* __restrict__ b_in,
    const float* __restrict__ W_proj,const float* __restrict__ b_proj,
    const float* __restrict__ W_gcn,
    short* __restrict__ hp, short* __restrict__ hinT_all,
    short* __restrict__ WgT, short* __restrict__ WpT)
{
    __shared__ __align__(16) short hb[128 * 66];   // [j][q], stride 66: bank-safe
    const int b = blockIdx.x, tid = threadIdx.x;
    if (b < 256) {
        const int n0 = b * 16;
        for (int i = tid; i < 16 * HH; i += 256) {
            const int q = i >> 7, j = i & 127, n = n0 + q;
            hp[n * HH + j] = f2b(b_proj[j]);
        }
    } else if (b < 272) {
        const int wb = b - 256;
        #pragma unroll
        for (int k = 0; k < 4; ++k) {
            const int idx = wb * 1024 + k * 256 + tid;   // = n*128 + kk
            const int n = idx >> 7, kk = idx & 127;
            WgT[idx] = f2b(W_gcn[kk * HH + n]);
            WpT[idx] = f2b(W_proj[kk * HH + n]);
        }
    } else {
        const int u = b - 272;
        const int t = u >> 6, n0 = (u & 63) * 64;
        // compute h_in for 64 nodes x 128 features into LDS (transposed).
        // consecutive lanes hold consecutive j (x/m broadcast, W coalesced);
        // stride-66 write bank = (j + q/2)%32 -> <=2 lanes/bank (free).
        for (int i = tid; i < 64 * HH; i += 256) {
            const int q = i >> 7, j = i & 127, n = n0 + q;
            float hv = x_seq[n * TT + t] * W_in[j] + m_seq[n * TT + t] * W_in[HH + j] + b_in[j];
            hv = hv > 0.f ? hv : 0.f;
            hb[j * 66 + q] = f2b(hv);
        }
        __syncthreads();
        // coalesced sigma-permuted stores: 8B chunks (2xu32 LDS reads — row
        // byte-stride 132 breaks u64 alignment; u32 banks (j+4k)%32, free).
        short* dst = hinT_all + (size_t)t * SLICE;
        for (int c = tid; c < 128 * 16; c += 256) {
            const int j = c >> 4, off = (c & 15) * 4;
            const int nb = n0 + off;
            const int tcol = (nb & ~31) | (((nb >> 2) & 3) << 3) | (((nb >> 4) & 1) << 2);
            const unsigned lo = *(const unsigned*)&hb[j * 66 + off];
            const unsigned hi = *(const unsigned*)&hb[j * 66 + off + 2];
            const u64 v = (u64)lo | ((u64)hi << 32);
            *(u64*)&dst[(size_t)j * NNP + tcol] = v;
        }
    }
}

// ===========================================================================
// Phase A: attention partials. 512 blocks x 256 thr (4 waves), up to 3
// co-resident blocks/CU (LDS 3x37KB, __launch_bounds__(256,3)).
// XCD-local indexing: split = bid>>6, qg = bid&63 -> bid%8 = qg%8, so all 8
// split-producers of a qg share one XCD's L2 (OpartB/lpart stay local).
// Wave owns ONE q-tile (16 rows).  Block stages its 512-key slice via LDS
// double-buffered K/V tiles, ONE barrier/tile.  Swapped QK^T -> in-register
// f2b softmax -> PV via sigma; l on the matrix pipe (ones column).
// O partials out bf16 via the per-wave LDS bounce.
// ===========================================================================
__global__ __launch_bounds__(256, 3) void attn_kernel(
    const short* __restrict__ hp, const short* __restrict__ hinT,
    short* __restrict__ OpartB, float* __restrict__ lpart)
{
    __shared__ __align__(16) char pool[37888];
    short* KtS = (short*)pool;                  // [2][32*136]  17408 B
    short* VtS = (short*)(pool + 17408);        // [2][128*40]  20480 B

    const int tid  = threadIdx.x;
    const int wave = tid >> 6, lane = tid & 63;
    const int ln = lane & 15, g = lane >> 4;
    const int split = blockIdx.x >> 6, qg = blockIdx.x & 63;   // XCD = qg%8
    const int q0 = qg * QB + wave * 16;
    const int kbase = split * KPB;

    // staging thread maps (256 threads, 16B/lane coalesced, 2 passes each)
    const int krow = tid >> 4, kcol = (tid & 15) * 8;   // rows 0..15 (+16)
    const int vrow = tid >> 2, vcol = (tid & 3) * 8;    // rows 0..63 (+64)

    // Q fragment (B-operand in swapped QK^T): 1 q-tile, proven layout
    short8 qf[4];
    #pragma unroll
    for (int kc = 0; kc < 4; ++kc)
        qf[kc] = *(const short8*)&hp[(q0 + ln) * HH + kc * 32 + g * 8];

    f32x4 oacc[8] = {};   // O[q = g*4 + r][d = dt*16 + ln]
    f32x4 lacc = {};      // l (ones-column accumulator, matrix pipe)
    short8 vone;
    #pragma unroll
    for (int e = 0; e < 8; ++e) vone[e] = (short)0x3F80;   // bf16 1.0

    short8 ksA0, ksA1, vsA0, vsA1;
    auto load_tile = [&](int kt_) {
        const int kb = kbase + kt_ * KT;
        ksA0 = *(const short8*)&hp  [(kb + krow) * HH + kcol];
        ksA1 = *(const short8*)&hp  [(kb + krow + 16) * HH + kcol];
        vsA0 = *(const short8*)&hinT[(size_t)vrow * NNP + kb + vcol];
        vsA1 = *(const short8*)&hinT[(size_t)(vrow + 64) * NNP + kb + vcol];
    };
    auto store_tile = [&](int b) {
        *(short8*)&KtS[b * 4352 + krow * 136 + kcol]        = ksA0;
        *(short8*)&KtS[b * 4352 + (krow + 16) * 136 + kcol] = ksA1;
        *(short8*)&VtS[b * 5120 + vrow * 40 + vcol]         = vsA0;
        *(short8*)&VtS[b * 5120 + (vrow + 64) * 40 + vcol]  = vsA1;
    };

    load_tile(0);
    store_tile(0);

    for (int kt = 0; kt < NTILES; ++kt) {
        const int b = kt & 1;
        __syncthreads();   // buf b staged; prev iter's frag reads drained (WAR)

        short8 kf[2][4], vf[8];
        #pragma unroll
        for (int kt2 = 0; kt2 < 2; ++kt2)
            #pragma unroll
            for (int kc = 0; kc < 4; ++kc)
                kf[kt2][kc] = *(const short8*)&KtS[b * 4352 + (kt2 * 16 + ln) * 136 + kc * 32 + g * 8];
        #pragma unroll
        for (int dt = 0; dt < 8; ++dt)
            vf[dt] = *(const short8*)&VtS[b * 5120 + (dt * 16 + ln) * 40 + g * 8];

        if (kt + 1 < NTILES) load_tile(kt + 1);   // global -> regs, overlaps compute

        // swapped scores: st[kt2][r] = S[key = kt2*16+g*4+r][q = q0+ln]
        f32x4 st[2] = {};
        __builtin_amdgcn_s_setprio(1);
        #pragma unroll
        for (int kt2 = 0; kt2 < 2; ++kt2)
            #pragma unroll
            for (int kc = 0; kc < 4; ++kc)
                st[kt2] = MFMA(kf[kt2][kc], qf[kc], st[kt2]);
        __builtin_amdgcn_s_setprio(0);

        // fixed-shift softmax numerators -> bf16 A-fragment (proven order)
        short8 pa;
        #pragma unroll
        for (int e = 0; e < 8; ++e) {
            const float s = (e < 4) ? st[0][e] : st[1][e - 4];
            pa[e] = f2b(__expf(s * SCALE - CSHIFT));
        }

        if (kt + 1 < NTILES) store_tile(b ^ 1);

        // PV (+ l via ones column): pa is the A-fragment in slot space
        __builtin_amdgcn_s_setprio(1);
        #pragma unroll
        for (int dt = 0; dt < 8; ++dt)
            oacc[dt] = MFMA(pa, vf[dt], oacc[dt]);
        lacc = MFMA(pa, vone, lacc);
        __builtin_amdgcn_s_setprio(0);
    }

    __syncthreads();   // all waves' LDS frag reads done -> pool reusable as bounce

    // l: ones-column output is col-replicated; row q = g*4 + r (proven D map)
    if (ln == 0) {
        #pragma unroll
        for (int r = 0; r < 4; ++r)
            lpart[split * NN + q0 + g * 4 + r] = lacc[r];
    }

    // O partials -> bf16 via per-wave LDS bounce (coalesced 16B/lane stores)
    short* bounce = (short*)pool + wave * 2048;   // 4KB/wave in dead Kt/Vt
    #pragma unroll
    for (int dt = 0; dt < 8; ++dt)
        #pragma unroll
        for (int r = 0; r < 4; ++r)
            bounce[(g * 4 + r) * 128 + dt * 16 + ln] = f2b(oacc[dt][r]);
    lds_fence();   // RAW: cross-lane bounce writes before row reads
    #pragma unroll
    for (int sub = 0; sub < 4; ++sub) {
        const int qrow = sub * 4 + (lane >> 4), chunk = lane & 15;
        const short8 rd = *(const short8*)&bounce[qrow * 128 + chunk * 8];
        *(short8*)&OpartB[((size_t)split * NN + q0 + qrow) * HH + chunk * 8] = rd;
    }
}

// ===========================================================================
// Phase B: merge 8 bf16 partials -> msg; h_new = relu(msg@Wg+b_gcn+h_in(t));
// pred -> out[:,t]; h_proj(t+1) -> hp.  (h_in precomputed in prep.)
// 256 blocks x 512 thr (8 waves, 2/SIMD — R6/R7-proven 8-wave GEMM content).
// XCD-local bijection: qg = (fb&7)+8*(fb>>5), sub = (fb>>3)&3 -> fb%8 = qg%8,
// so this block reads OpartB/lpart from its own XCD's L2.
// ===========================================================================
__global__ __launch_bounds__(512) void fuse_kernel(
    const short* __restrict__ OpartB, const float* __restrict__ lpart,
    short* __restrict__ hp,
    const short* __restrict__ WgT, const short* __restrict__ WpT,
    const float* __restrict__ b_gcn, const float* __restrict__ b_proj,
    const float* __restrict__ W_out, const float* __restrict__ b_out,
    const float* __restrict__ x_seq, const float* __restrict__ m_seq,
    const float* __restrict__ W_in,  const float* __restrict__ b_in,
    float* __restrict__ out, int t)
{
    __shared__ __align__(16) short msgb[16 * 136];
    __shared__ __align__(16) short hnb[16 * 136];
    __shared__ float larr[16];
    __shared__ float ppd[8 * 16];

    const int tid = threadIdx.x;
    const int wave = tid >> 6, lane = tid & 63;
    const int ln = lane & 15, g = lane >> 4;
    const int fb = blockIdx.x;
    const int qg64 = (fb & 7) + 8 * (fb >> 5);          // qg%8 = fb%8 (XCD-local)
    const int qb = qg64 * 64 + ((fb >> 3) & 3) * 16;    // bijective over 0..255

    if (tid < 16) {
        float l = 0.f;
        #pragma unroll
        for (int sp = 0; sp < SPLITS; ++sp) l += lpart[sp * NN + qb + tid];
        larr[tid] = 1.0f / l;
    }
    __syncthreads();

    // merge 8 bf16 partials -> msg (256 thr path, proven)
    if (tid < 256) {
        const int q = tid >> 4, c8 = (tid & 15) * 8;
        float s[8] = {0.f, 0.f, 0.f, 0.f, 0.f, 0.f, 0.f, 0.f};
        #pragma unroll
        for (int sp = 0; sp < SPLITS; ++sp) {
            const short8 v = *(const short8*)&OpartB[((size_t)sp * NN + qb + q) * HH + c8];
            #pragma unroll
            for (int k = 0; k < 8; ++k) s[k] += b2f(v[k]);
        }
        const float inv = larr[q];
        short* mp = &msgb[q * 136 + c8];
        #pragma unroll
        for (int k = 0; k < 8; ++k) mp[k] = f2b(s[k] * inv);
    }
    __syncthreads();

    // GEMM1 (8 waves, nt = wave): h_new = relu(msg@Wg + b_gcn + h_in(t))
    {
        short8 af[4];
        #pragma unroll
        for (int kc = 0; kc < 4; ++kc)
            af[kc] = *(const short8*)&msgb[ln * 136 + kc * 32 + g * 8];
        f32x4 c = {};
        #pragma unroll
        for (int kc = 0; kc < 4; ++kc)
            c = MFMA(af[kc], *(const short8*)&WgT[(wave * 16 + ln) * HH + kc * 32 + g * 8], c);
        const int j = wave * 16 + ln;
        const float bg = b_gcn[j], wo = W_out[j];
        const float wj0 = W_in[j], wj1 = W_in[HH + j], bj = b_in[j];
        float pr[4];
        #pragma unroll
        for (int r = 0; r < 4; ++r) {
            const int q = g * 4 + r;
            float hv = x_seq[(qb + q) * TT + t] * wj0 + m_seq[(qb + q) * TT + t] * wj1 + bj;
            hv = hv > 0.f ? hv : 0.f;
            float v = c[r] + bg + b2f(f2b(hv));
            v = v > 0.f ? v : 0.f;
            hnb[q * 136 + j] = f2b(v);
            pr[r] = v * wo;
        }
        #pragma unroll
        for (int r = 0; r < 4; ++r) {
            float p = pr[r];
            p += __shfl_xor(p, 1); p += __shfl_xor(p, 2);
            p += __shfl_xor(p, 4); p += __shfl_xor(p, 8);
            if (ln == 0) ppd[wave * 16 + g * 4 + r] = p;
        }
    }
    __syncthreads();   // hnb + ppd complete

    if (tid < 16) {
        float s = b_out[0];
        #pragma unroll
        for (int w = 0; w < 8; ++w) s += ppd[w * 16 + tid];
        out[(qb + tid) * TT + t] = s;
    }

    if (t < TT - 1) {
        // GEMM2 (8 waves, nt = wave): h_proj(t+1) = h_new @ W_proj + b_proj
        short8 hf[4];
        #pragma unroll
        for (int kc = 0; kc < 4; ++kc)
            hf[kc] = *(const short8*)&hnb[ln * 136 + kc * 32 + g * 8];
        f32x4 c = {};
        #pragma unroll
        for (int kc = 0; kc < 4; ++kc)
            c = MFMA(hf[kc], *(const short8*)&WpT[(wave * 16 + ln) * HH + kc * 32 + g * 8], c);
        const float bp = b_proj[wave * 16 + ln];
        #pragma unroll
        for (int r = 0; r < 4; ++r)
            hp[(qb + g * 4 + r) * HH + wave * 16 + ln] = f2b(c[r] + bp);
    }
}

// ===========================================================================
extern "C" void kernel_launch(void* const* d_in, const int* in_sizes, int n_in,
                              void* d_out, int out_size, void* d_ws, size_t ws_size,
                              hipStream_t stream) {
    const float* x_seq  = (const float*)d_in[0];
    const float* m_seq  = (const float*)d_in[1];
    const float* W_in   = (const float*)d_in[2];
    const float* b_in   = (const float*)d_in[3];
    const float* W_proj = (const float*)d_in[4];
    const float* b_proj = (const float*)d_in[5];
    const float* W_gcn  = (const float*)d_in[6];
    const float* b_gcn  = (const float*)d_in[7];
    const float* W_out  = (const float*)d_in[8];
    const float* b_out  = (const float*)d_in[9];
    float* out = (float*)d_out;

    // ws carve (~100 MB of the 256 MiB workspace):
    //   hp @0 | WgT/WpT/lpart @3MB | OpartB @4MB (8MB) | hinT_all @32MB (67MB)
    char* base = (char*)d_ws;
    const size_t MB = 1 << 20;
    short* hp       = (short*)(base + 0 * MB);
    short* WgT      = (short*)(base + 3 * MB);
    short* WpT      = (short*)(base + 3 * MB + 32768);
    float* lpart    = (float*)(base + 3 * MB + 65536);   // 8*4096*4 = 128 KB
    short* OpartB   = (short*)(base + 4 * MB);           // 8*4096*128*2 = 8 MB
    short* hinT_all = (short*)(base + 32 * MB);          // 64*128*4160*2 ≈ 67 MB

    prep_kernel<<<272 + 64 * 64, 256, 0, stream>>>(x_seq, m_seq, W_in, b_in,
                                                   W_proj, b_proj, W_gcn,
                                                   hp, hinT_all, WgT, WpT);

    for (int t = 0; t < TT; ++t) {
        const short* hinT_t = hinT_all + (size_t)t * SLICE;
        attn_kernel<<<(NN / QB) * SPLITS, 256, 0, stream>>>(hp, hinT_t, OpartB, lpart);
        fuse_kernel<<<NN / 16, 512, 0, stream>>>(OpartB, lpart, hp,
                                                 WgT, WpT, b_gcn, b_proj, W_out, b_out,
                                                 x_seq, m_seq, W_in, b_in, out, t);
    }
}